// Round 1
// baseline (902.481 us; speedup 1.0000x reference)
//
#include <hip/hip_runtime.h>

#define D_MODEL 4096
#define SHARDS 8
#define TPB 4  // tokens per block

typedef float f32x4 __attribute__((ext_vector_type(4)));

// Fused embedding gather: out[t,d] = W[tok[t],d] + sum_s b[s,d].
// Block = 256 threads; each thread owns 4 float4 slots of the 4096-wide row.
// Fast path (all blocks but the tail): load ALL 16 float4 of the block's 4
// W-rows into registers before any add/store -> 16 independent 16B loads in
// flight per thread (latency hiding), then bias-add + nontemporal store (the
// 64 MiB output stream is never re-read; keep it out of L2 so the bias table
// and duplicate token rows stay resident).
__global__ __launch_bounds__(256) void embed_fused_kernel(const int* __restrict__ tok,
                                                          const float* __restrict__ W,
                                                          const float* __restrict__ b,
                                                          float* __restrict__ out,
                                                          int T) {
    const int tid = threadIdx.x;
    const int t0  = blockIdx.x * TPB;
    if (t0 >= T) return;

    const bool full = (t0 + TPB <= T);

    // This block's 4 token ids as one 16B load (block-uniform).
    int rows[TPB];
    if (full) {
        const int4 r4 = ((const int4*)tok)[blockIdx.x];
        rows[0] = r4.x; rows[1] = r4.y; rows[2] = r4.z; rows[3] = r4.w;
    } else {
#pragma unroll
        for (int j = 0; j < TPB; ++j) rows[j] = (t0 + j < T) ? tok[t0 + j] : 0;
    }

    // Per-thread bias sums for its 4 slots: bb[i] = sum_s b[s, (tid + i*256)*4..]
    const f32x4* __restrict__ b4 = (const f32x4*)b;
    f32x4 bb[4];
#pragma unroll
    for (int i = 0; i < 4; ++i) {
        const int d = tid + i * 256;            // float4 index in [0,1024)
        f32x4 acc = b4[d];
#pragma unroll
        for (int s = 1; s < SHARDS; ++s) acc += b4[s * (D_MODEL / 4) + d];
        bb[i] = acc;
    }

    if (full) {
        // Row base pointers.
        const f32x4* __restrict__ Wr[TPB];
#pragma unroll
        for (int j = 0; j < TPB; ++j)
            Wr[j] = (const f32x4*)(W + (long long)rows[j] * D_MODEL);

        // Phase 1: issue all 16 independent loads.
        f32x4 w[TPB][4];
#pragma unroll
        for (int j = 0; j < TPB; ++j)
#pragma unroll
            for (int i = 0; i < 4; ++i)
                w[j][i] = Wr[j][tid + i * 256];

        // Phase 2: bias add + streaming store.
#pragma unroll
        for (int j = 0; j < TPB; ++j) {
            f32x4* __restrict__ out4 = (f32x4*)(out + (long long)(t0 + j) * D_MODEL);
#pragma unroll
            for (int i = 0; i < 4; ++i) {
                const f32x4 v = w[j][i] + bb[i];
                __builtin_nontemporal_store(v, &out4[tid + i * 256]);
            }
        }
    } else {
        // Tail block: safe scalar-row path.
        for (int j = 0; j < TPB; ++j) {
            const int t = t0 + j;
            if (t >= T) break;
            const f32x4* __restrict__ Wrow = (const f32x4*)(W + (long long)rows[j] * D_MODEL);
            f32x4* __restrict__ out4       = (f32x4*)(out + (long long)t * D_MODEL);
#pragma unroll
            for (int i = 0; i < 4; ++i) {
                const int idx = tid + i * 256;
                const f32x4 v = Wrow[idx] + bb[i];
                __builtin_nontemporal_store(v, &out4[idx]);
            }
        }
    }
}

extern "C" void kernel_launch(void* const* d_in, const int* in_sizes, int n_in,
                              void* d_out, int out_size, void* d_ws, size_t ws_size,
                              hipStream_t stream) {
    const int*   tok = (const int*)d_in[0];    // x, int32, T elements
    const float* W   = (const float*)d_in[1];  // [50400, 4096] fp32
    const float* b   = (const float*)d_in[2];  // [8, 4096] fp32
    float* out = (float*)d_out;                // [T, 4096] fp32

    const int T = in_sizes[0];                 // 4096 tokens
    const int grid = (T + TPB - 1) / TPB;      // 1024 blocks -> 4 blocks/CU, 16 waves/CU

    embed_fused_kernel<<<grid, 256, 0, stream>>>(tok, W, b, out, T);
}